// Round 14
// baseline (186.241 us; speedup 1.0000x reference)
//
#include <hip/hip_runtime.h>
#include <hip/hip_bf16.h>
#include <math.h>

#define D_DIM 512
#define TM    128
#define TN    256
#define BK    128
#define NMAIN 1152        // 16*8*9 padded triangular tiles (1056 real)
#define NBAND 64          // 8192 / 128

typedef int i32x4 __attribute__((ext_vector_type(4)));
typedef unsigned long long u64;

// ---- helpers ---------------------------------------------------------------

__device__ inline u64 shfl_xor_u64(u64 x, int m) {
    int lo = __shfl_xor((int)(unsigned)(x & 0xFFFFFFFFull), m, 64);
    int hi = __shfl_xor((int)(unsigned)(x >> 32), m, 64);
    return ((u64)(unsigned)hi << 32) | (u64)(unsigned)lo;
}

__device__ inline void async16(unsigned char* lds, const unsigned char* g) {
    __builtin_amdgcn_global_load_lds(
        (const __attribute__((address_space(1))) void*)g,
        (__attribute__((address_space(3))) void*)lds,
        16, 0, 0);
}

// ---- kernel 1: row L2-normalize -> int8 (x127), init best + counters -------

__global__ __launch_bounds__(256) void normalize_rows(
        const float* __restrict__ in, unsigned char* __restrict__ xb,
        float* __restrict__ inv_norm, u64* __restrict__ best,
        float* __restrict__ acc, int* __restrict__ gcnt,
        int* __restrict__ bandcnt) {
    const int row  = blockIdx.x * 4 + (threadIdx.x >> 6);
    const int lane = threadIdx.x & 63;
    if (blockIdx.x == 0) {
        if (threadIdx.x < NBAND) bandcnt[threadIdx.x] = 0;
        if (threadIdx.x == NBAND)     acc[0]  = 0.f;
        if (threadIdx.x == NBAND + 1) gcnt[0] = 0;
    }
    const float4* rp = (const float4*)(in + (size_t)row * D_DIM) + lane * 2;
    float4 a = rp[0], b = rp[1];
    float s = a.x*a.x + a.y*a.y + a.z*a.z + a.w*a.w
            + b.x*b.x + b.y*b.y + b.z*b.z + b.w*b.w;
    #pragma unroll
    for (int m = 1; m <= 32; m <<= 1) s += __shfl_xor(s, m, 64);
    float inv = 1.0f / fmaxf(sqrtf(s), 1e-8f);
    if (lane == 0) {
        inv_norm[row] = inv;
        best[row] = 0ull;   // below any real packed key
    }
    float sc = inv * 127.0f;   // int8 symmetric quant; |x_norm|<=1 -> no clamp
    int q0 = __float2int_rn(a.x*sc), q1 = __float2int_rn(a.y*sc);
    int q2 = __float2int_rn(a.z*sc), q3 = __float2int_rn(a.w*sc);
    int q4 = __float2int_rn(b.x*sc), q5 = __float2int_rn(b.y*sc);
    int q6 = __float2int_rn(b.z*sc), q7 = __float2int_rn(b.w*sc);
    int lo = (q0 & 255) | ((q1 & 255) << 8) | ((q2 & 255) << 16) | ((q3 & 255) << 24);
    int hi = (q4 & 255) | ((q5 & 255) << 8) | ((q6 & 255) << 16) | ((q7 & 255) << 24);
    ((int2*)(xb + (size_t)row * D_DIM))[lane] = make_int2(lo, hi);
}

// ---- kernel 2: R11 gemm core + LAST-CONTRIBUTOR band finalize --------------
// No waiter blocks (R13's 256 spinners stole CU slots -> producers lost
// 2/CU co-residency). Instead, each band tick returns the old count; the
// block seeing old == expected-1 finalizes that band's 128 rows (exact fp32
// distances, best[] via coherent RMW). No __threadfence anywhere (R10's L2
// nuke); ordering comes from the __syncthreads vmcnt(0) drain before the
// ticks (R12/R13-validated). Producers never wait -> deadlock-free.
// expected[r] = 34 + r/2 (sum = 3168 = 3*1056, validated R12/R13).

__global__ __launch_bounds__(256, 2) void gemm_argmax(
        const unsigned char* __restrict__ X, u64* __restrict__ best,
        const float* __restrict__ in, const float* __restrict__ inv_norm,
        float* __restrict__ acc, int* __restrict__ gcnt,
        int* __restrict__ bandcnt, float* __restrict__ out, int B) {
    __shared__ unsigned char As[TM * BK];     // 16 KB
    __shared__ unsigned char Bs[TN * BK];     // 32 KB
    __shared__ u64 rmerge[TM * 2];            // 2 KB
    __shared__ u64 cmerge[TN * 2];            // 4 KB
    __shared__ int oldc[3];
    __shared__ float sbf[4];

    const int l    = blockIdx.x;
    const int t    = threadIdx.x;
    const int lane = t & 63;
    const int w    = t >> 6;

    // decode padded id: col-group q (4 cols of width-256), per-col cnt 8(q+1)
    int q = (int)(sqrtf((float)l / 16.0f + 0.25f) - 0.5f);
    while (16 * (q + 1) * (q + 2) <= l) ++q;
    while (16 * q * (q + 1) > l) --q;
    int rrem = l - 16 * q * (q + 1);
    int cw   = 8 * (q + 1);
    int c    = rrem / cw;
    int bi   = rrem - c * cw;           // row tile (128-wide), bi%8 == l%8
    int bj   = 4 * q + c;               // col tile (256-wide)
    if (bi > 2 * bj + 1) return;        // padding (not counted in expected)
    const int m0 = bi * TM;
    const int n0 = bj * TN;

    const int wm   = w >> 1, wn = w & 1;
    const int qr   = lane & 15;
    const int quad = lane >> 4;

    const int rS   = t >> 3;
    const int gSrc = ((t & 7) ^ ((t >> 3) & 7)) * 16;
    const unsigned char* gA = X + (size_t)(m0 + rS) * D_DIM + gSrc;
    const unsigned char* gB = X + (size_t)(n0 + rS) * D_DIM + gSrc;

    i32x4 accm[4][8];
    #pragma unroll
    for (int mi = 0; mi < 4; mi++)
        #pragma unroll
        for (int ni = 0; ni < 8; ni++)
            accm[mi][ni] = (i32x4){0, 0, 0, 0};

    for (int k0 = 0; k0 < D_DIM; k0 += BK) {
        #pragma unroll
        for (int j = 0; j < 4; j++)
            async16(As + j * 4096 + t * 16, gA + (size_t)(j * 32) * D_DIM + k0);
        #pragma unroll
        for (int j = 0; j < 8; j++)
            async16(Bs + j * 4096 + t * 16, gB + (size_t)(j * 32) * D_DIM + k0);
        __syncthreads();

        #pragma unroll
        for (int ks = 0; ks < 2; ks++) {
            i32x4 av[4], bv[8];
            #pragma unroll
            for (int mi = 0; mi < 4; mi++) {
                int r   = wm * 64 + mi * 16 + qr;
                int pos = (ks * 4 + quad) ^ (r & 7);
                av[mi] = *(const i32x4*)(As + r * BK + pos * 16);
            }
            #pragma unroll
            for (int ni = 0; ni < 8; ni++) {
                int r   = wn * 128 + ni * 16 + qr;
                int pos = (ks * 4 + quad) ^ (r & 7);
                bv[ni] = *(const i32x4*)(Bs + r * BK + pos * 16);
            }
            #pragma unroll
            for (int mi = 0; mi < 4; mi++)
                #pragma unroll
                for (int ni = 0; ni < 8; ni++)
                    accm[mi][ni] = __builtin_amdgcn_mfma_i32_16x16x64_i8(
                        av[mi], bv[ni], accm[mi][ni], 0, 0, 0);
        }
        __syncthreads();
    }

    // ---- row-side argmax over this tile's 256 cols (diag masked) ----------
    const int colg_base = n0 + wn * 128 + qr;
    #pragma unroll
    for (int mi = 0; mi < 4; mi++) {
        #pragma unroll
        for (int r = 0; r < 4; r++) {
            const int rowl = wm * 64 + mi * 16 + quad * 4 + r;
            const int rowg = m0 + rowl;
            u64 key = 0ull;
            #pragma unroll
            for (int ni = 0; ni < 8; ni++) {
                int colg = colg_base + ni * 16;
                if (colg == rowg) continue;
                unsigned bd = (unsigned)accm[mi][ni][r] + 0x80000000u;
                u64 k = ((u64)bd << 32) | (u64)(0xFFFFFFFFu - (unsigned)colg);
                key = key > k ? key : k;
            }
            #pragma unroll
            for (int m = 1; m <= 8; m <<= 1) {
                u64 o = shfl_xor_u64(key, m);
                key = key > o ? key : o;
            }
            if (qr == 0) rmerge[rowl * 2 + wn] = key;
        }
    }

    // ---- col-side argmax (symmetry; diag masked here too) ------------------
    #pragma unroll
    for (int ni = 0; ni < 8; ni++) {
        const int colg = colg_base + ni * 16;
        u64 key = 0ull;
        #pragma unroll
        for (int mi = 0; mi < 4; mi++) {
            #pragma unroll
            for (int r = 0; r < 4; r++) {
                int rowg = m0 + wm * 64 + mi * 16 + quad * 4 + r;
                if (rowg == colg) continue;
                unsigned bd = (unsigned)accm[mi][ni][r] + 0x80000000u;
                u64 k = ((u64)bd << 32) | (u64)(0xFFFFFFFFu - (unsigned)rowg);
                key = key > k ? key : k;
            }
        }
        u64 o = shfl_xor_u64(key, 16); key = key > o ? key : o;
        o     = shfl_xor_u64(key, 32); key = key > o ? key : o;
        if (quad == 0) cmerge[(wn * 128 + ni * 16 + qr) * 2 + wm] = key;
    }
    __syncthreads();
    if (t < TM) {
        u64 a = rmerge[t * 2], b = rmerge[t * 2 + 1];
        u64 k = a > b ? a : b;
        atomicMax(&best[m0 + t], k);
    }
    {   // all 256 threads: one column each
        u64 ca = cmerge[t * 2], cb = cmerge[t * 2 + 1];
        u64 ck = ca > cb ? ca : cb;
        atomicMax(&best[n0 + t], ck);
    }

    // ---- band tickets (barrier's vmcnt(0) drain orders the atomics above) --
    __syncthreads();
    if (t == 0) oldc[0] = atomicAdd(&bandcnt[bi], 1);
    if (t == 1) oldc[1] = atomicAdd(&bandcnt[2 * bj], 1);
    if (t == 2) oldc[2] = atomicAdd(&bandcnt[2 * bj + 1], 1);
    __syncthreads();

    // ---- last contributor per band: exact fp32 finalize ---------------------
    const int bands[3] = {bi, 2 * bj, 2 * bj + 1};
    float lsum = 0.f;
    int nf = 0;
    #pragma unroll
    for (int s = 0; s < 3; s++) {
        const int band = bands[s];
        if (oldc[s] != 34 + (band >> 1) - 1) continue;
        nf++;
        for (int i = 0; i < 32; i++) {              // 4 waves x 32 rows = 128
            const int row = band * TM + w * 32 + i;
            u64 k   = atomicMax(&best[row], 0ull);  // device-coherent read
            int nbr = (int)(0xFFFFFFFFu - (unsigned)(k & 0xFFFFFFFFull));
            float ir  = inv_norm[row];
            float inb = inv_norm[nbr];
            const float4* rp = (const float4*)(in + (size_t)row * D_DIM) + lane * 2;
            const float4* np = (const float4*)(in + (size_t)nbr * D_DIM) + lane * 2;
            float4 r0 = rp[0], r1 = rp[1], q0 = np[0], q1 = np[1];
            float d0 = r0.x*ir - q0.x*inb + 1e-8f, d1 = r0.y*ir - q0.y*inb + 1e-8f;
            float d2 = r0.z*ir - q0.z*inb + 1e-8f, d3 = r0.w*ir - q0.w*inb + 1e-8f;
            float d4 = r1.x*ir - q1.x*inb + 1e-8f, d5 = r1.y*ir - q1.y*inb + 1e-8f;
            float d6 = r1.z*ir - q1.z*inb + 1e-8f, d7 = r1.w*ir - q1.w*inb + 1e-8f;
            float sd = d0*d0 + d1*d1 + d2*d2 + d3*d3 + d4*d4 + d5*d5 + d6*d6 + d7*d7;
            #pragma unroll
            for (int m = 1; m <= 32; m <<= 1) sd += __shfl_xor(sd, m, 64);
            if (lane == 0) lsum += logf(sqrtf(sd) + 1e-8f);
        }
    }
    if (__syncthreads_count(nf > 0) == 0) return;   // no finalize in this block

    if (lane == 0) sbf[w] = lsum;
    __syncthreads();
    if (t == 0 && nf > 0) atomicAdd(acc, sbf[0] + sbf[1] + sbf[2] + sbf[3]);
    __syncthreads();                 // vmcnt(0) drain orders acc before gcnt
    if (t == 0 && nf > 0) {
        int old = atomicAdd(gcnt, nf);
        if (old + nf == NBAND) {
            float tot = atomicAdd(acc, 0.0f);       // coherent read of final sum
            out[0] = -tot / (float)B;
        }
    }
}

// ---- launch ----------------------------------------------------------------

extern "C" void kernel_launch(void* const* d_in, const int* in_sizes, int n_in,
                              void* d_out, int out_size, void* d_ws, size_t ws_size,
                              hipStream_t stream) {
    const float* in = (const float*)d_in[0];
    const int B = in_sizes[0] / D_DIM;          // 8192

    char* w = (char*)d_ws;
    unsigned char* xb = (unsigned char*)w;                     // B*D int8
    float* invn    = (float*)(w + (size_t)B * D_DIM);
    u64*   best    = (u64*)(w + (size_t)B * D_DIM + (size_t)B * 4);
    float* acc     = (float*)(w + (size_t)B * D_DIM + (size_t)B * 4 + (size_t)B * 8);
    int*   gcnt    = (int*)(acc + 1);
    int*   bandcnt = (int*)(acc + 2);
    float* out     = (float*)d_out;

    normalize_rows<<<B / 4, 256, 0, stream>>>(in, xb, invn, best, acc, gcnt, bandcnt);
    gemm_argmax<<<NMAIN, 256, 0, stream>>>(xb, best, in, invn,
                                           acc, gcnt, bandcnt, out, B);
}

// Round 15
// 116.266 us; speedup vs baseline: 1.6019x; 1.6019x over previous
//
#include <hip/hip_runtime.h>
#include <hip/hip_bf16.h>
#include <math.h>

#define D_DIM 512
#define TM    128
#define TN    256
#define BK    128

typedef int i32x4 __attribute__((ext_vector_type(4)));
typedef unsigned long long u64;

// ---- helpers ---------------------------------------------------------------

__device__ inline u64 shfl_xor_u64(u64 x, int m) {
    int lo = __shfl_xor((int)(unsigned)(x & 0xFFFFFFFFull), m, 64);
    int hi = __shfl_xor((int)(unsigned)(x >> 32), m, 64);
    return ((u64)(unsigned)hi << 32) | (u64)(unsigned)lo;
}

__device__ inline void async16(unsigned char* lds, const unsigned char* g) {
    __builtin_amdgcn_global_load_lds(
        (const __attribute__((address_space(1))) void*)g,
        (__attribute__((address_space(3))) void*)lds,
        16, 0, 0);
}

// ---- kernel 1: row L2-normalize -> int8 (x127), init best/acc/cnt ----------

__global__ __launch_bounds__(256) void normalize_rows(
        const float* __restrict__ in, unsigned char* __restrict__ xb,
        float* __restrict__ inv_norm, u64* __restrict__ best,
        float* __restrict__ acc, int* __restrict__ cnt) {
    const int row  = blockIdx.x * 4 + (threadIdx.x >> 6);
    const int lane = threadIdx.x & 63;
    if (blockIdx.x == 0 && threadIdx.x == 0) { acc[0] = 0.f; cnt[0] = 0; }
    const float4* rp = (const float4*)(in + (size_t)row * D_DIM) + lane * 2;
    float4 a = rp[0], b = rp[1];
    float s = a.x*a.x + a.y*a.y + a.z*a.z + a.w*a.w
            + b.x*b.x + b.y*b.y + b.z*b.z + b.w*b.w;
    #pragma unroll
    for (int m = 1; m <= 32; m <<= 1) s += __shfl_xor(s, m, 64);
    float inv = 1.0f / fmaxf(sqrtf(s), 1e-8f);
    if (lane == 0) {
        inv_norm[row] = inv;
        best[row] = 0ull;   // below any real packed key
    }
    float sc = inv * 127.0f;   // int8 symmetric quant; |x_norm|<=1 -> no clamp
    int q0 = __float2int_rn(a.x*sc), q1 = __float2int_rn(a.y*sc);
    int q2 = __float2int_rn(a.z*sc), q3 = __float2int_rn(a.w*sc);
    int q4 = __float2int_rn(b.x*sc), q5 = __float2int_rn(b.y*sc);
    int q6 = __float2int_rn(b.z*sc), q7 = __float2int_rn(b.w*sc);
    int lo = (q0 & 255) | ((q1 & 255) << 8) | ((q2 & 255) << 16) | ((q3 & 255) << 24);
    int hi = (q4 & 255) | ((q5 & 255) << 8) | ((q6 & 255) << 16) | ((q7 & 255) << 24);
    ((int2*)(xb + (size_t)row * D_DIM))[lane] = make_int2(lo, hi);
}

// ---- kernel 2: 128x256-tile int8 GEMM + argmax (R11, best measured) --------
// int8 16x16x64 MFMA, BK=128, b128 swizzled LDS (~zero conflicts), padded-
// triangular schedule keeping bi%8 == blockIdx%8 (per-XCD L2 A-band).
// Coverage: tiles bi <= 2bj+1; duplicate dots give identical integer keys
// (u64 max idempotent); diagonal masked in both reductions.
// NOTE (R12-R14): do NOT fuse the neighbor gather into this kernel — every
// variant (waiters, last-contributor) regressed via occupancy/register
// cliffs; the 128-AGPR accumulator leaves zero slack.

__global__ __launch_bounds__(256, 2) void gemm_argmax(
        const unsigned char* __restrict__ X, u64* __restrict__ best) {
    __shared__ unsigned char As[TM * BK];     // 16 KB
    __shared__ unsigned char Bs[TN * BK];     // 32 KB
    __shared__ u64 rmerge[TM * 2];            // 2 KB
    __shared__ u64 cmerge[TN * 2];            // 4 KB

    // decode padded id: col-group q (4 cols of width-256), per-col cnt 8(q+1)
    int l = blockIdx.x;
    int q = (int)(sqrtf((float)l / 16.0f + 0.25f) - 0.5f);
    while (16 * (q + 1) * (q + 2) <= l) ++q;
    while (16 * q * (q + 1) > l) --q;
    int rrem = l - 16 * q * (q + 1);
    int cw   = 8 * (q + 1);
    int c    = rrem / cw;
    int bi   = rrem - c * cw;           // row tile (128-wide), bi%8 == l%8
    int bj   = 4 * q + c;               // col tile (256-wide)
    if (bi > 2 * bj + 1) return;        // padding / fully-below-diagonal
    const int m0 = bi * TM;
    const int n0 = bj * TN;

    const int t    = threadIdx.x;
    const int lane = t & 63;
    const int w    = t >> 6;
    const int wm   = w >> 1, wn = w & 1;
    const int qr   = lane & 15;
    const int quad = lane >> 4;

    const int rS   = t >> 3;
    const int gSrc = ((t & 7) ^ ((t >> 3) & 7)) * 16;
    const unsigned char* gA = X + (size_t)(m0 + rS) * D_DIM + gSrc;
    const unsigned char* gB = X + (size_t)(n0 + rS) * D_DIM + gSrc;

    i32x4 accm[4][8];
    #pragma unroll
    for (int mi = 0; mi < 4; mi++)
        #pragma unroll
        for (int ni = 0; ni < 8; ni++)
            accm[mi][ni] = (i32x4){0, 0, 0, 0};

    for (int k0 = 0; k0 < D_DIM; k0 += BK) {
        #pragma unroll
        for (int j = 0; j < 4; j++)
            async16(As + j * 4096 + t * 16, gA + (size_t)(j * 32) * D_DIM + k0);
        #pragma unroll
        for (int j = 0; j < 8; j++)
            async16(Bs + j * 4096 + t * 16, gB + (size_t)(j * 32) * D_DIM + k0);
        __syncthreads();

        #pragma unroll
        for (int ks = 0; ks < 2; ks++) {
            i32x4 av[4], bv[8];
            #pragma unroll
            for (int mi = 0; mi < 4; mi++) {
                int r   = wm * 64 + mi * 16 + qr;
                int pos = (ks * 4 + quad) ^ (r & 7);
                av[mi] = *(const i32x4*)(As + r * BK + pos * 16);
            }
            #pragma unroll
            for (int ni = 0; ni < 8; ni++) {
                int r   = wn * 128 + ni * 16 + qr;
                int pos = (ks * 4 + quad) ^ (r & 7);
                bv[ni] = *(const i32x4*)(Bs + r * BK + pos * 16);
            }
            #pragma unroll
            for (int mi = 0; mi < 4; mi++)
                #pragma unroll
                for (int ni = 0; ni < 8; ni++)
                    accm[mi][ni] = __builtin_amdgcn_mfma_i32_16x16x64_i8(
                        av[mi], bv[ni], accm[mi][ni], 0, 0, 0);
        }
        __syncthreads();
    }

    // ---- row-side argmax over this tile's 256 cols (diag masked) ----------
    const int colg_base = n0 + wn * 128 + qr;
    #pragma unroll
    for (int mi = 0; mi < 4; mi++) {
        #pragma unroll
        for (int r = 0; r < 4; r++) {
            const int rowl = wm * 64 + mi * 16 + quad * 4 + r;
            const int rowg = m0 + rowl;
            u64 key = 0ull;
            #pragma unroll
            for (int ni = 0; ni < 8; ni++) {
                int colg = colg_base + ni * 16;
                if (colg == rowg) continue;
                unsigned bd = (unsigned)accm[mi][ni][r] + 0x80000000u;
                u64 k = ((u64)bd << 32) | (u64)(0xFFFFFFFFu - (unsigned)colg);
                key = key > k ? key : k;
            }
            #pragma unroll
            for (int m = 1; m <= 8; m <<= 1) {
                u64 o = shfl_xor_u64(key, m);
                key = key > o ? key : o;
            }
            if (qr == 0) rmerge[rowl * 2 + wn] = key;
        }
    }

    // ---- col-side argmax (symmetry; diag masked here too) ------------------
    #pragma unroll
    for (int ni = 0; ni < 8; ni++) {
        const int colg = colg_base + ni * 16;
        u64 key = 0ull;
        #pragma unroll
        for (int mi = 0; mi < 4; mi++) {
            #pragma unroll
            for (int r = 0; r < 4; r++) {
                int rowg = m0 + wm * 64 + mi * 16 + quad * 4 + r;
                if (rowg == colg) continue;
                unsigned bd = (unsigned)accm[mi][ni][r] + 0x80000000u;
                u64 k = ((u64)bd << 32) | (u64)(0xFFFFFFFFu - (unsigned)rowg);
                key = key > k ? key : k;
            }
        }
        u64 o = shfl_xor_u64(key, 16); key = key > o ? key : o;
        o     = shfl_xor_u64(key, 32); key = key > o ? key : o;
        if (quad == 0) cmerge[(wn * 128 + ni * 16 + qr) * 2 + wm] = key;
    }
    __syncthreads();
    if (t < TM) {
        u64 a = rmerge[t * 2], b = rmerge[t * 2 + 1];
        u64 k = a > b ? a : b;
        atomicMax(&best[m0 + t], k);
    }
    {   // all 256 threads: one column each
        u64 ca = cmerge[t * 2], cb = cmerge[t * 2 + 1];
        u64 ck = ca > cb ? ca : cb;
        atomicMax(&best[n0 + t], ck);
    }
}

// ---- kernel 3: exact fp32 distance + fused mean (256-block cheap ticket) ---

__global__ __launch_bounds__(256) void neighbor_reduce(
        const float* __restrict__ in, const float* __restrict__ inv_norm,
        const u64* __restrict__ best, float* __restrict__ acc,
        int* __restrict__ cnt, float* __restrict__ out, int B) {
    const int wave = threadIdx.x >> 6;
    const int lane = threadIdx.x & 63;
    float lsum = 0.f;
    #pragma unroll
    for (int rr = 0; rr < 8; rr++) {
        const int row = blockIdx.x * 32 + wave * 8 + rr;
        u64 k   = best[row];
        int nbr = (int)(0xFFFFFFFFu - (unsigned)(k & 0xFFFFFFFFull));
        float ir  = inv_norm[row];
        float inb = inv_norm[nbr];
        const float4* rp = (const float4*)(in + (size_t)row * D_DIM) + lane * 2;
        const float4* np = (const float4*)(in + (size_t)nbr * D_DIM) + lane * 2;
        float4 r0 = rp[0], r1 = rp[1], q0 = np[0], q1 = np[1];
        float d0 = r0.x*ir - q0.x*inb + 1e-8f, d1 = r0.y*ir - q0.y*inb + 1e-8f;
        float d2 = r0.z*ir - q0.z*inb + 1e-8f, d3 = r0.w*ir - q0.w*inb + 1e-8f;
        float d4 = r1.x*ir - q1.x*inb + 1e-8f, d5 = r1.y*ir - q1.y*inb + 1e-8f;
        float d6 = r1.z*ir - q1.z*inb + 1e-8f, d7 = r1.w*ir - q1.w*inb + 1e-8f;
        float s = d0*d0 + d1*d1 + d2*d2 + d3*d3 + d4*d4 + d5*d5 + d6*d6 + d7*d7;
        #pragma unroll
        for (int m = 1; m <= 32; m <<= 1) s += __shfl_xor(s, m, 64);
        if (lane == 0) lsum += logf(sqrtf(s) + 1e-8f);
    }
    __shared__ float sb[4];
    if (lane == 0) sb[wave] = lsum;
    __syncthreads();
    if (threadIdx.x == 0) {
        float partial = sb[0] + sb[1] + sb[2] + sb[3];
        atomicAdd(acc, partial);
        __threadfence();
        int done = atomicAdd(cnt, 1);
        if (done == gridDim.x - 1) {
            __threadfence();
            float tot = atomicAdd(acc, 0.0f);   // device-scope read of final sum
            out[0] = -tot / (float)B;
        }
    }
}

// ---- launch ----------------------------------------------------------------

extern "C" void kernel_launch(void* const* d_in, const int* in_sizes, int n_in,
                              void* d_out, int out_size, void* d_ws, size_t ws_size,
                              hipStream_t stream) {
    const float* in = (const float*)d_in[0];
    const int B = in_sizes[0] / D_DIM;          // 8192
    const int nblk = 16 * 8 * 9;                // 1152 padded tiles (8 col-groups)

    char* w = (char*)d_ws;
    unsigned char* xb = (unsigned char*)w;                     // B*D int8
    float* invn = (float*)(w + (size_t)B * D_DIM);
    u64*   best = (u64*)(w + (size_t)B * D_DIM + (size_t)B * 4);
    float* acc  = (float*)(w + (size_t)B * D_DIM + (size_t)B * 4 + (size_t)B * 8);
    int*   cnt  = (int*)(acc + 1);
    float* out  = (float*)d_out;

    normalize_rows<<<B / 4, 256, 0, stream>>>(in, xb, invn, best, acc, cnt);
    gemm_argmax<<<nblk, 256, 0, stream>>>(xb, best);
    neighbor_reduce<<<B / 32, 256, 0, stream>>>(in, invn, best, acc, cnt, out, B);
}